// Round 18
// baseline (152.663 us; speedup 1.0000x reference)
//
#include <hip/hip_runtime.h>
#include <cstdint>
#include <cstddef>

#define B_  4
#define L_  4096
#define N_  1024
#define D_  768
#define H_  12
#define HD_ 64

// 0.125 * log2(e): softmax runs in exp2 domain, scale folded into Q-GEMM epilogue
#define QK_SCALE 0.18033688011112042f

typedef __bf16 bf16x4 __attribute__((ext_vector_type(4)));
typedef __bf16 bf16x8 __attribute__((ext_vector_type(8)));
typedef float  f32x4  __attribute__((ext_vector_type(4)));
typedef unsigned int u32;

static __device__ __forceinline__ f32x4 mfma16(bf16x8 a, bf16x8 b, f32x4 c) {
    return __builtin_amdgcn_mfma_f32_16x16x32_bf16(a, b, c, 0, 0, 0);
}

static __device__ __forceinline__ void async_cp16(const __bf16* g, const __bf16* l) {
    __builtin_amdgcn_global_load_lds(
        (const __attribute__((address_space(1))) u32*)g,
        (__attribute__((address_space(3))) u32*)l, 16, 0, 0);
}

static __device__ __forceinline__ u32 pkbf(float lo, float hi) {
    union { __bf16 b[2]; u32 u; } r;
    r.b[0] = (__bf16)lo; r.b[1] = (__bf16)hi;
    return r.u;
}

// single v_exp_f32 (2^x), no pre-multiply
static __device__ __forceinline__ float exp2fast(float x) {
#if __has_builtin(__builtin_amdgcn_exp2f)
    return __builtin_amdgcn_exp2f(x);
#else
    float r;
    asm("v_exp_f32 %0, %1" : "=v"(r) : "v"(x));
    return r;
#endif
}

// ---------------- fused prologue: LN, casts, weff, compaction-at-source ----------------

static __device__ __forceinline__ void ln_row(const float* __restrict__ xr,
                                              const float* __restrict__ g,
                                              const float* __restrict__ be,
                                              __bf16* __restrict__ yr)
{
    const int tid = threadIdx.x, lane = tid & 63, wid = tid >> 6;
    float4 v = make_float4(0.f, 0.f, 0.f, 0.f);
    if (tid < 192) v = *(const float4*)(xr + tid * 4);
    float s  = v.x + v.y + v.z + v.w;
    float s2 = v.x * v.x + v.y * v.y + v.z * v.z + v.w * v.w;
#pragma unroll
    for (int off = 32; off > 0; off >>= 1) {
        s  += __shfl_down(s, off);
        s2 += __shfl_down(s2, off);
    }
    __shared__ float red[8];
    if (lane == 0) { red[wid] = s; red[4 + wid] = s2; }
    __syncthreads();
    s  = red[0] + red[1] + red[2] + red[3];
    s2 = red[4] + red[5] + red[6] + red[7];
    const float mean = s * (1.f / D_);
    const float var  = s2 * (1.f / D_) - mean * mean;
    const float rstd = rsqrtf(var + 1e-5f);
    if (tid < 192) {
        const float4 gv = *(const float4*)(g + tid * 4);
        const float4 bv = *(const float4*)(be + tid * 4);
        bf16x4 o;
        o[0] = (__bf16)((v.x - mean) * rstd * gv.x + bv.x);
        o[1] = (__bf16)((v.y - mean) * rstd * gv.y + bv.y);
        o[2] = (__bf16)((v.z - mean) * rstd * gv.z + bv.z);
        o[3] = (__bf16)((v.w - mean) * rstd * gv.w + bv.w);
        *(bf16x4*)(yr + tid * 4) = o;
    }
}

// Region row: compute compacted pos inline; if unmasked write LN'd row -> rk_c[pos]
// and raw bf16 cast -> regb_c[pos]. Masked rows write nothing.
static __device__ __forceinline__ void ln_cast_region(const float* __restrict__ xr,
                                                      const int* __restrict__ maskb, int n,
                                                      const float* __restrict__ g,
                                                      const float* __restrict__ be,
                                                      __bf16* __restrict__ rk_base,
                                                      __bf16* __restrict__ regb_base)
{
    const int tid = threadIdx.x, lane = tid & 63, wid = tid >> 6;
    const bool keep = maskb[n] != 0;

    __shared__ int cnt[4];
    int pos = 0;
    for (int i0 = 0; i0 < n; i0 += 256) {
        const int i = i0 + tid;
        const int mv = (i < n) ? maskb[i] : 0;
        const unsigned long long bal = __ballot(mv != 0);
        if (lane == 0) cnt[wid] = __popcll(bal);
        __syncthreads();
        pos += cnt[0] + cnt[1] + cnt[2] + cnt[3];
        __syncthreads();
    }
    if (!keep) return;   // uniform across block

    float4 v = make_float4(0.f, 0.f, 0.f, 0.f);
    if (tid < 192) v = *(const float4*)(xr + tid * 4);
    float s  = v.x + v.y + v.z + v.w;
    float s2 = v.x * v.x + v.y * v.y + v.z * v.z + v.w * v.w;
#pragma unroll
    for (int off = 32; off > 0; off >>= 1) {
        s  += __shfl_down(s, off);
        s2 += __shfl_down(s2, off);
    }
    __shared__ float red[8];
    if (lane == 0) { red[wid] = s; red[4 + wid] = s2; }
    __syncthreads();
    s  = red[0] + red[1] + red[2] + red[3];
    s2 = red[4] + red[5] + red[6] + red[7];
    const float mean = s * (1.f / D_);
    const float var  = s2 * (1.f / D_) - mean * mean;
    const float rstd = rsqrtf(var + 1e-5f);
    if (tid < 192) {
        const float4 gv = *(const float4*)(g + tid * 4);
        const float4 bv = *(const float4*)(be + tid * 4);
        bf16x4 o, c;
        o[0] = (__bf16)((v.x - mean) * rstd * gv.x + bv.x);
        o[1] = (__bf16)((v.y - mean) * rstd * gv.y + bv.y);
        o[2] = (__bf16)((v.z - mean) * rstd * gv.z + bv.z);
        o[3] = (__bf16)((v.w - mean) * rstd * gv.w + bv.w);
        c[0] = (__bf16)v.x; c[1] = (__bf16)v.y; c[2] = (__bf16)v.z; c[3] = (__bf16)v.w;
        *(bf16x4*)(rk_base + (size_t)pos * D_ + tid * 4) = o;
        *(bf16x4*)(regb_base + (size_t)pos * D_ + tid * 4) = c;
    }
}

static __device__ __forceinline__ void cast4(const float* __restrict__ in,
                                             __bf16* __restrict__ out, int blk)
{
    const int i = (blk * 256 + threadIdx.x) * 4;
    const float4 v = *(const float4*)(in + i);
    bf16x4 o;
    o[0] = (__bf16)v.x; o[1] = (__bf16)v.y; o[2] = (__bf16)v.z; o[3] = (__bf16)v.w;
    *(bf16x4*)(out + i) = o;
}

static __device__ __forceinline__ void weff4(const float* __restrict__ W,
                                             const float* __restrict__ Bm,
                                             const float* __restrict__ Am,
                                             __bf16* __restrict__ out, int blk)
{
    const int idx = (blk * 256 + threadIdx.x) * 4;
    const int o = idx / D_, i = idx - o * D_;
    const float4 w = *(const float4*)(W + idx);
    float sx = 0.f, sy = 0.f, sz = 0.f, sw = 0.f;
#pragma unroll
    for (int r = 0; r < 8; ++r) {
        const float b = Bm[o * 8 + r];
        const float4 a = *(const float4*)(Am + r * D_ + i);
        sx += b * a.x; sy += b * a.y; sz += b * a.z; sw += b * a.w;
    }
    bf16x4 ov;
    ov[0] = (__bf16)(w.x + 2.f * sx);
    ov[1] = (__bf16)(w.y + 2.f * sy);
    ov[2] = (__bf16)(w.z + 2.f * sz);
    ov[3] = (__bf16)(w.w + 2.f * sw);
    *(bf16x4*)(out + idx) = ov;
}

static __device__ __forceinline__ void count_mask(const int* __restrict__ maskb,
                                                  int* __restrict__ Nv)
{
    const int tid = threadIdx.x, lane = tid & 63, wid = tid >> 6;
    const int4 mv = *(const int4*)(maskb + tid * 4);
    int c = (mv.x != 0) + (mv.y != 0) + (mv.z != 0) + (mv.w != 0);
#pragma unroll
    for (int off = 32; off > 0; off >>= 1) c += __shfl_down(c, off);
    __shared__ int w4[4];
    if (lane == 0) w4[wid] = c;
    __syncthreads();
    if (tid == 0) *Nv = w4[0] + w4[1] + w4[2] + w4[3];
}

__global__ __launch_bounds__(256) void prologue_kernel(
    const float* __restrict__ text, const float* __restrict__ regions,
    const int* __restrict__ mask,
    const float* __restrict__ Wq, const float* __restrict__ Aq, const float* __restrict__ Bq,
    const float* __restrict__ Wv, const float* __restrict__ Av, const float* __restrict__ Bv,
    const float* __restrict__ Wk, const float* __restrict__ Wo,
    const float* __restrict__ gq, const float* __restrict__ bq,
    const float* __restrict__ gkv, const float* __restrict__ bkv,
    __bf16* __restrict__ tq, __bf16* __restrict__ rk, __bf16* __restrict__ regb,
    __bf16* __restrict__ Weq, __bf16* __restrict__ Wev,
    __bf16* __restrict__ Wkb, __bf16* __restrict__ Wob,
    int* __restrict__ NvArr)
{
    int bx = blockIdx.x;
    if (bx < B_ * L_) { ln_row(text + (size_t)bx * D_, gq, bq, tq + (size_t)bx * D_); return; }
    bx -= B_ * L_;
    if (bx < B_ * N_) {
        const int b = bx >> 10, n = bx & (N_ - 1);
        ln_cast_region(regions + (size_t)bx * D_, mask + b * N_, n, gkv, bkv,
                       rk + (size_t)b * N_ * D_, regb + (size_t)b * N_ * D_);
        return;
    }
    bx -= B_ * N_;
    if (bx < 576) { weff4(Wq, Bq, Aq, Weq, bx); return; }
    bx -= 576;
    if (bx < 576) { weff4(Wv, Bv, Av, Wev, bx); return; }
    bx -= 576;
    if (bx < 576) { cast4(Wk, Wkb, bx); return; }
    bx -= 576;
    if (bx < 576) { cast4(Wo, Wob, bx); return; }
    bx -= 576;
    count_mask(mask + bx * N_, NvArr + bx);
}

// ---------------- LDS-staged 128x128 GEMM: 3-buffer counted-vmcnt pipeline ----------------
// T4 recipe: stage(t+2) each step, wait vmcnt(4) + raw s_barrier (never 0 till last step).
// LDS tile [128][32] bf16, slot-swizzled (chunk c at slot c ^ ((row>>1)&3), pre-swizzled src).
// C[m][o] = sum_k A[m][k]*W[o][k]
// EPI==0: bf16 row-major | EPI==1: bf16 transposed (B,H,HD,N) | EPI==2: +resid+bias fp32 | EPI==3: *QK_SCALE bf16
template <int EPI, typename CT>
static __device__ __forceinline__ void gemm_body(__bf16* sm,
                                                 const __bf16* __restrict__ A,
                                                 const __bf16* __restrict__ W,
                                                 CT* __restrict__ C,
                                                 const float* __restrict__ resid,
                                                 const float* __restrict__ bias,
                                                 int mb0, int nb0)
{
    const int tid = threadIdx.x, wid = tid >> 6, lane = tid & 63;
    const int lr = lane & 15, g = lane >> 4;
    const int wm = wid >> 1, wn = wid & 1;
    const int NSTEP = D_ / 32;   // 24

    auto skey2 = [](int row) { return (row >> 1) & 3; };

    auto stage = [&](int kb, int buf) {
        __bf16* as = sm + buf * 8192;
        __bf16* bs = as + 4096;
#pragma unroll
        for (int j = 0; j < 2; ++j) {
            const int s = wid * 64 + lane + j * 256;
            const int row = s >> 2;
            const int c = (s & 3) ^ skey2(row);     // pre-swizzled source chunk
            const int dst = (wid * 64 + j * 256) * 8;
            async_cp16(A + (size_t)(mb0 + row) * D_ + kb * 32 + c * 8, as + dst);
            async_cp16(W + (size_t)(nb0 + row) * D_ + kb * 32 + c * 8, bs + dst);
        }
    };

    f32x4 acc[4][4] = {};

    stage(0, 0);
    stage(1, 1);

    for (int kb = 0; kb < NSTEP; ++kb) {
        if (kb < NSTEP - 1) asm volatile("s_waitcnt vmcnt(4)" ::: "memory");
        else                asm volatile("s_waitcnt vmcnt(0)" ::: "memory");
        __builtin_amdgcn_s_barrier();

        if (kb + 2 < NSTEP) stage(kb + 2, (kb + 2) % 3);

        const __bf16* as = sm + (kb % 3) * 8192;
        const __bf16* bs = as + 4096;
        bf16x8 av[4], wv[4];
#pragma unroll
        for (int mi = 0; mi < 4; ++mi) {
            const int row = wm * 64 + mi * 16 + lr;
            av[mi] = *(const bf16x8*)(as + row * 32 + (g ^ skey2(row)) * 8);
        }
#pragma unroll
        for (int oi = 0; oi < 4; ++oi) {
            const int row = wn * 64 + oi * 16 + lr;
            wv[oi] = *(const bf16x8*)(bs + row * 32 + (g ^ skey2(row)) * 8);
        }
        __builtin_amdgcn_s_setprio(1);
#pragma unroll
        for (int mi = 0; mi < 4; ++mi)
#pragma unroll
            for (int oi = 0; oi < 4; ++oi)
                acc[mi][oi] = mfma16(av[mi], wv[oi], acc[mi][oi]);
        __builtin_amdgcn_s_setprio(0);
    }

#pragma unroll
    for (int mi = 0; mi < 4; ++mi) {
#pragma unroll
        for (int oi = 0; oi < 4; ++oi) {
#pragma unroll
            for (int r = 0; r < 4; ++r) {
                const int m = mb0 + wm * 64 + mi * 16 + g * 4 + r;
                const int o = nb0 + wn * 64 + oi * 16 + lr;
                float v = acc[mi][oi][r];
                if (EPI == 2)
                    v += resid[(size_t)m * D_ + o] + bias[o];
                if (EPI == 3)
                    v *= QK_SCALE;
                if (EPI == 1) {
                    const size_t idx =
                        ((size_t)((m >> 10) * H_ + (o >> 6)) * HD_ + (o & 63)) * N_ + (m & (N_ - 1));
                    C[idx] = (CT)v;
                } else {
                    C[(size_t)m * D_ + o] = (CT)v;
                }
            }
        }
    }
}

// Fused Q+K+V projection GEMMs; 1-D grid, XCD-chunked swizzle on the Q part.
__global__ __launch_bounds__(256) void gemm_qkv(const __bf16* __restrict__ tq,
                                                const __bf16* __restrict__ Weq,
                                                __bf16* __restrict__ Qb,
                                                const __bf16* __restrict__ rk,
                                                const __bf16* __restrict__ Wkb,
                                                __bf16* __restrict__ Kb,
                                                const __bf16* __restrict__ regb,
                                                const __bf16* __restrict__ Wev,
                                                __bf16* __restrict__ Vt,
                                                const int* __restrict__ NvArr)
{
    extern __shared__ __bf16 smem[];
    const int gid = blockIdx.x;
    if (gid < 768) {
        const int xcd = gid & 7, pos = gid >> 3;
        const int s = xcd * 96 + pos;          // bijective: 768 = 8*96
        gemm_body<3, __bf16>(smem, tq, Weq, Qb, nullptr, nullptr, (s / 6) * 128, (s % 6) * 128);
    } else if (gid < 960) {
        const int lin = gid - 768;             // 0..191 : 32 M-blocks x 6 ny
        const int m0 = (lin / 6) * 128, ny = (lin % 6) * 128;
        if ((m0 & (N_ - 1)) >= NvArr[m0 >> 10]) return;   // uniform early-exit
        gemm_body<0, __bf16>(smem, rk, Wkb, Kb, nullptr, nullptr, m0, ny);
    } else {
        const int lin = gid - 960;
        const int m0 = (lin / 6) * 128, ny = (lin % 6) * 128;
        if ((m0 & (N_ - 1)) >= NvArr[m0 >> 10]) return;
        gemm_body<1, __bf16>(smem, regb, Wev, Vt, nullptr, nullptr, m0, ny);
    }
}

__global__ __launch_bounds__(256) void gemm_out(const __bf16* __restrict__ A,
                                                const __bf16* __restrict__ W,
                                                float* __restrict__ C,
                                                const float* __restrict__ resid,
                                                const float* __restrict__ bias)
{
    extern __shared__ __bf16 smem[];
    const int xcd = blockIdx.x & 7, pos = blockIdx.x >> 3;
    const int s = xcd * 96 + pos;              // bijective: 768 = 8*96
    gemm_body<2, float>(smem, A, W, C, resid, bias, (s / 6) * 128, (s % 6) * 128);
}

// ---------------- flash attention over COMPACTED keys: 3-buffer counted-vmcnt, 4 q-frags ----------------
// Block = (b, h, 256 q), 4 waves x 64 q (4 q-frags of 16). Q pre-scaled by 0.125*log2e (exp2 domain).
// T4 schedule: stage(t+2) after barrier, vmcnt(4) steady / vmcnt(0) last. Incremented staging pointers.
// Per-tile overhead (kf/vf LDS reads, barriers, stage issue) amortized over 2x queries vs 2-frag.
// Compaction => validity is (key index < Nv); only LAST tile compares (cndmask to exact 0 after exp).
// No max-tracking: |S|<=~3 for LN'd inputs; fully-masked batch -> Nv=0 -> output 0.
__global__ __launch_bounds__(256, 3) void attn_kernel(const __bf16* __restrict__ Qb,
                                                      const __bf16* __restrict__ Kb,
                                                      const __bf16* __restrict__ Vt,
                                                      const int* __restrict__ NvArr,
                                                      __bf16* __restrict__ ctx)
{
    const int bq = blockIdx.x, h = blockIdx.y, b = blockIdx.z;
    const int tid = threadIdx.x, wid = tid >> 6, lane = tid & 63;
    const int lr = lane & 15, g = lane >> 4;

    const int Nv = NvArr[b];
    const int ntiles = (Nv + 63) >> 6;

    __shared__ __align__(16) __bf16 kbuf[3][4096];   // 64 keys x 64 d, slot-swizzled
    __shared__ __align__(16) __bf16 vbuf[3][4096];   // 64 d x 64 keys, slot-swizzled

    const int hoff = h * HD_;
    const int bN = b * N_;
    const size_t bhHD = ((size_t)b * H_ + h) * HD_;

    // slot-swizzle key: spreads the 16 concurrently-read rows over all 8 slots
    auto skey = [](int row) { return (row & 3) | (((row >> 3) & 1) << 2); };

    // incremented staging pointers (4 loads/stage)
    const int s0 = wid * 64 + lane, s1 = s0 + 256;
    const int row0 = s0 >> 3, row1 = s1 >> 3;
    const int ks0 = (s0 & 7) ^ skey(row0), ks1 = (s1 & 7) ^ skey(row1);
    const __bf16* kc0 = Kb + (size_t)(bN + row0) * D_ + hoff + ks0 * 8;
    const __bf16* kc1 = Kb + (size_t)(bN + row1) * D_ + hoff + ks1 * 8;
    const __bf16* vc0 = Vt + (bhHD + row0) * N_ + ks0 * 8;
    const __bf16* vc1 = Vt + (bhHD + row1) * N_ + ks1 * 8;
    const int d0 = (wid * 64) * 8, d1 = (wid * 64 + 256) * 8;
    int stage_t = 0;

    auto stage = [&]() {
        const int bsel = stage_t % 3;
        async_cp16(kc0, &kbuf[bsel][d0]);
        async_cp16(kc1, &kbuf[bsel][d1]);
        async_cp16(vc0, &vbuf[bsel][d0]);
        async_cp16(vc1, &vbuf[bsel][d1]);
        kc0 += 64 * D_; kc1 += 64 * D_; vc0 += 64; vc1 += 64;
        ++stage_t;
    };

    const int q0 = bq * 256 + wid * 64;
    bf16x8 qa[4][2];
#pragma unroll
    for (int qf = 0; qf < 4; ++qf) {
        const __bf16* qptr = Qb + ((size_t)b * L_ + q0 + qf * 16 + lr) * D_ + hoff + g * 8;
        qa[qf][0] = *(const bf16x8*)(qptr);
        qa[qf][1] = *(const bf16x8*)(qptr + 32);
    }

    f32x4 acc[4][4] = {};
    float ssum[4] = {0.f, 0.f, 0.f, 0.f};

    if (ntiles > 0) {
        stage();
        if (ntiles > 1) stage();

        for (int t = 0; t < ntiles; ++t) {
            if (t < ntiles - 1) asm volatile("s_waitcnt vmcnt(4)" ::: "memory");
            else                asm volatile("s_waitcnt vmcnt(0)" ::: "memory");
            __builtin_amdgcn_s_barrier();

            if (t + 2 < ntiles) stage();

            const __bf16* kb = kbuf[t % 3];
            const __bf16* vb = vbuf[t % 3];

            // K fragments: rows permuted so lane's S values == its PV A-fragment keys
            bf16x8 kf[4][2];
#pragma unroll
            for (int kt = 0; kt < 4; ++kt) {
                const int row = (kt >> 1) * 32 + (lr >> 2) * 8 + (kt & 1) * 4 + (lr & 3);
                const int kx = skey(row);
#pragma unroll
                for (int kc = 0; kc < 2; ++kc)
                    kf[kt][kc] = *(const bf16x8*)((const char*)kb + row * 128 + ((((kc * 4) + g) ^ kx) << 4));
            }

            const bool lastTile = (t == ntiles - 1);

            // per q-frag: QK^T then softmax immediately (caps s4/p liveness)
            bf16x8 pa[4][2];
#pragma unroll
            for (int qf = 0; qf < 4; ++qf) {
                // S^T = K·Q^T : lane holds q=lr, keys (kt>>1)*32 + g*8 + (kt&1)*4 + r
                f32x4 s4[4];
                __builtin_amdgcn_s_setprio(1);
#pragma unroll
                for (int kt = 0; kt < 4; ++kt) {
                    f32x4 z = {};
                    s4[kt] = mfma16(kf[kt][0], qa[qf][0], z);
                    s4[kt] = mfma16(kf[kt][1], qa[qf][1], s4[kt]);
                }
                __builtin_amdgcn_s_setprio(0);

                // exp2-domain no-max softmax; last tile zeroes pad keys (exact 0)
                float p[4][4];
                float tsum = 0.f;
                if (lastTile) {
#pragma unroll
                    for (int kt = 0; kt < 4; ++kt) {
                        const int jb = t * 64 + (kt >> 1) * 32 + g * 8 + (kt & 1) * 4;
#pragma unroll
                        for (int r = 0; r < 4; ++r) {
                            const float e = exp2fast(s4[kt][r]);
                            p[kt][r] = (jb + r < Nv) ? e : 0.f;
                            tsum += p[kt][r];
                        }
                    }
                } else {
#pragma unroll
                    for (int kt = 0; kt < 4; ++kt)
#pragma unroll
                        for (int r = 0; r < 4; ++r) {
                            p[kt][r] = exp2fast(s4[kt][r]);
                            tsum += p[kt][r];
                        }
                }
                tsum += __shfl_xor(tsum, 16);
                tsum += __shfl_xor(tsum, 32);
                ssum[qf] += tsum;

                // pack P into PV A-fragments (no cross-lane needed by construction)
#pragma unroll
                for (int c = 0; c < 2; ++c) {
                    union { u32 w[4]; bf16x8 v; } pu;
#pragma unroll
                    for (int m = 0; m < 4; ++m) {
                        const int kt = 2 * c + (m >> 1);
                        pu.w[m] = pkbf(p[kt][2 * (m & 1)], p[kt][2 * (m & 1) + 1]);
                    }
                    pa[qf][c] = pu.v;
                }
            }

            // PV: each vf load feeds 4 q-frags
            __builtin_amdgcn_s_setprio(1);
#pragma unroll
            for (int dt = 0; dt < 4; ++dt) {
                const int d = dt * 16 + lr;
                const int vx = skey(d);
#pragma unroll
                for (int c = 0; c < 2; ++c) {
                    const bf16x8 vf = *(const bf16x8*)((const char*)vb + d * 128 + ((((c * 4) + g) ^ vx) << 4));
                    acc[0][dt] = mfma16(pa[0][c], vf, acc[0][dt]);
                    acc[1][dt] = mfma16(pa[1][c], vf, acc[1][dt]);
                    acc[2][dt] = mfma16(pa[2][c], vf, acc[2][dt]);
                    acc[3][dt] = mfma16(pa[3][c], vf, acc[3][dt]);
                }
            }
            __builtin_amdgcn_s_setprio(0);
        }
    }

#pragma unroll
    for (int qf = 0; qf < 4; ++qf) {
        const float inv = (ssum[qf] > 0.f) ? 1.f / ssum[qf] : 0.f;
        float iv[4];
#pragma unroll
        for (int r = 0; r < 4; ++r) iv[r] = __shfl(inv, g * 4 + r);
#pragma unroll
        for (int dt = 0; dt < 4; ++dt)
#pragma unroll
            for (int r = 0; r < 4; ++r) {
                const int q = q0 + qf * 16 + g * 4 + r;
                ctx[((size_t)b * L_ + q) * D_ + hoff + dt * 16 + lr] = (__bf16)(acc[qf][dt][r] * iv[r]);
            }
    }
}

extern "C" void kernel_launch(void* const* d_in, const int* in_sizes, int n_in,
                              void* d_out, int out_size, void* d_ws, size_t ws_size,
                              hipStream_t stream)
{
    const float* text    = (const float*)d_in[0];
    const float* regions = (const float*)d_in[1];
    const int*   mask    = (const int*)d_in[2];
    const float* Wq  = (const float*)d_in[3];
    const float* Aq  = (const float*)d_in[4];
    const float* Bq  = (const float*)d_in[5];
    const float* Wk  = (const float*)d_in[6];
    const float* Wv  = (const float*)d_in[7];
    const float* Av  = (const float*)d_in[8];
    const float* Bv  = (const float*)d_in[9];
    const float* Wo  = (const float*)d_in[10];
    const float* bo  = (const float*)d_in[11];
    const float* gq  = (const float*)d_in[12];
    const float* bq  = (const float*)d_in[13];
    const float* gkv = (const float*)d_in[14];
    const float* bkv = (const float*)d_in[15];

    const size_t BLD = (size_t)B_ * L_ * D_;
    const size_t BND = (size_t)B_ * N_ * D_;
    const size_t DD  = (size_t)D_ * D_;
    __bf16* ws   = (__bf16*)d_ws;
    __bf16* tq   = ws;                 // BLD
    __bf16* rk   = tq + BLD;           // BND (compacted rows)
    __bf16* Qb   = rk + BND;           // BLD
    __bf16* Kb   = Qb + BLD;           // BND (compacted rows)
    __bf16* Vt   = Kb + BND;           // BND (compacted cols)
    __bf16* ctx  = Vt + BND;           // BLD
    __bf16* regb = ctx + BLD;          // BND (compacted rows)
    __bf16* Weq  = regb + BND;         // DD
    __bf16* Wev  = Weq + DD;           // DD
    __bf16* Wkb  = Wev + DD;           // DD
    __bf16* Wob  = Wkb + DD;           // DD
    int* NvArr   = (int*)(Wob + DD);   // B ints

    const int smB = 49152;  // 3-buffer dynamic LDS for gemm kernels
    const int nProBlocks = B_ * L_ + B_ * N_ + 576 * 4 + B_;

    prologue_kernel<<<dim3(nProBlocks), 256, 0, stream>>>(
        text, regions, mask, Wq, Aq, Bq, Wv, Av, Bv, Wk, Wo,
        gq, bq, gkv, bkv, tq, rk, regb, Weq, Wev, Wkb, Wob, NvArr);
    gemm_qkv<<<dim3(1152), 256, smB, stream>>>(tq, Weq, Qb, rk, Wkb, Kb, regb, Wev, Vt, NvArr);
    attn_kernel<<<dim3(L_ / 256, H_, B_), 256, 0, stream>>>(Qb, Kb, Vt, NvArr, ctx);
    gemm_out<<<dim3(768), 256, smB, stream>>>(ctx, Wob, (float*)d_out, text, bo);
}

// Round 19
// 133.352 us; speedup vs baseline: 1.1448x; 1.1448x over previous
//
#include <hip/hip_runtime.h>
#include <cstdint>
#include <cstddef>

#define B_  4
#define L_  4096
#define N_  1024
#define D_  768
#define H_  12
#define HD_ 64

// 0.125 * log2(e): softmax runs in exp2 domain, scale folded into Q-GEMM epilogue
#define QK_SCALE 0.18033688011112042f

typedef __bf16 bf16x4 __attribute__((ext_vector_type(4)));
typedef __bf16 bf16x8 __attribute__((ext_vector_type(8)));
typedef float  f32x4  __attribute__((ext_vector_type(4)));
typedef unsigned int u32;

static __device__ __forceinline__ f32x4 mfma16(bf16x8 a, bf16x8 b, f32x4 c) {
    return __builtin_amdgcn_mfma_f32_16x16x32_bf16(a, b, c, 0, 0, 0);
}

static __device__ __forceinline__ void async_cp16(const __bf16* g, const __bf16* l) {
    __builtin_amdgcn_global_load_lds(
        (const __attribute__((address_space(1))) u32*)g,
        (__attribute__((address_space(3))) u32*)l, 16, 0, 0);
}

static __device__ __forceinline__ u32 pkbf(float lo, float hi) {
    union { __bf16 b[2]; u32 u; } r;
    r.b[0] = (__bf16)lo; r.b[1] = (__bf16)hi;
    return r.u;
}

// single v_exp_f32 (2^x), no pre-multiply
static __device__ __forceinline__ float exp2fast(float x) {
#if __has_builtin(__builtin_amdgcn_exp2f)
    return __builtin_amdgcn_exp2f(x);
#else
    float r;
    asm("v_exp_f32 %0, %1" : "=v"(r) : "v"(x));
    return r;
#endif
}

// ---------------- fused prologue: LN, casts, weff, compaction-at-source ----------------

static __device__ __forceinline__ void ln_row(const float* __restrict__ xr,
                                              const float* __restrict__ g,
                                              const float* __restrict__ be,
                                              __bf16* __restrict__ yr)
{
    const int tid = threadIdx.x, lane = tid & 63, wid = tid >> 6;
    float4 v = make_float4(0.f, 0.f, 0.f, 0.f);
    if (tid < 192) v = *(const float4*)(xr + tid * 4);
    float s  = v.x + v.y + v.z + v.w;
    float s2 = v.x * v.x + v.y * v.y + v.z * v.z + v.w * v.w;
#pragma unroll
    for (int off = 32; off > 0; off >>= 1) {
        s  += __shfl_down(s, off);
        s2 += __shfl_down(s2, off);
    }
    __shared__ float red[8];
    if (lane == 0) { red[wid] = s; red[4 + wid] = s2; }
    __syncthreads();
    s  = red[0] + red[1] + red[2] + red[3];
    s2 = red[4] + red[5] + red[6] + red[7];
    const float mean = s * (1.f / D_);
    const float var  = s2 * (1.f / D_) - mean * mean;
    const float rstd = rsqrtf(var + 1e-5f);
    if (tid < 192) {
        const float4 gv = *(const float4*)(g + tid * 4);
        const float4 bv = *(const float4*)(be + tid * 4);
        bf16x4 o;
        o[0] = (__bf16)((v.x - mean) * rstd * gv.x + bv.x);
        o[1] = (__bf16)((v.y - mean) * rstd * gv.y + bv.y);
        o[2] = (__bf16)((v.z - mean) * rstd * gv.z + bv.z);
        o[3] = (__bf16)((v.w - mean) * rstd * gv.w + bv.w);
        *(bf16x4*)(yr + tid * 4) = o;
    }
}

// Region row: compute compacted pos inline; if unmasked write LN'd row -> rk_c[pos]
// and raw bf16 cast -> regb_c[pos]. Masked rows write nothing.
static __device__ __forceinline__ void ln_cast_region(const float* __restrict__ xr,
                                                      const int* __restrict__ maskb, int n,
                                                      const float* __restrict__ g,
                                                      const float* __restrict__ be,
                                                      __bf16* __restrict__ rk_base,
                                                      __bf16* __restrict__ regb_base)
{
    const int tid = threadIdx.x, lane = tid & 63, wid = tid >> 6;
    const bool keep = maskb[n] != 0;

    __shared__ int cnt[4];
    int pos = 0;
    for (int i0 = 0; i0 < n; i0 += 256) {
        const int i = i0 + tid;
        const int mv = (i < n) ? maskb[i] : 0;
        const unsigned long long bal = __ballot(mv != 0);
        if (lane == 0) cnt[wid] = __popcll(bal);
        __syncthreads();
        pos += cnt[0] + cnt[1] + cnt[2] + cnt[3];
        __syncthreads();
    }
    if (!keep) return;   // uniform across block

    float4 v = make_float4(0.f, 0.f, 0.f, 0.f);
    if (tid < 192) v = *(const float4*)(xr + tid * 4);
    float s  = v.x + v.y + v.z + v.w;
    float s2 = v.x * v.x + v.y * v.y + v.z * v.z + v.w * v.w;
#pragma unroll
    for (int off = 32; off > 0; off >>= 1) {
        s  += __shfl_down(s, off);
        s2 += __shfl_down(s2, off);
    }
    __shared__ float red[8];
    if (lane == 0) { red[wid] = s; red[4 + wid] = s2; }
    __syncthreads();
    s  = red[0] + red[1] + red[2] + red[3];
    s2 = red[4] + red[5] + red[6] + red[7];
    const float mean = s * (1.f / D_);
    const float var  = s2 * (1.f / D_) - mean * mean;
    const float rstd = rsqrtf(var + 1e-5f);
    if (tid < 192) {
        const float4 gv = *(const float4*)(g + tid * 4);
        const float4 bv = *(const float4*)(be + tid * 4);
        bf16x4 o, c;
        o[0] = (__bf16)((v.x - mean) * rstd * gv.x + bv.x);
        o[1] = (__bf16)((v.y - mean) * rstd * gv.y + bv.y);
        o[2] = (__bf16)((v.z - mean) * rstd * gv.z + bv.z);
        o[3] = (__bf16)((v.w - mean) * rstd * gv.w + bv.w);
        c[0] = (__bf16)v.x; c[1] = (__bf16)v.y; c[2] = (__bf16)v.z; c[3] = (__bf16)v.w;
        *(bf16x4*)(rk_base + (size_t)pos * D_ + tid * 4) = o;
        *(bf16x4*)(regb_base + (size_t)pos * D_ + tid * 4) = c;
    }
}

static __device__ __forceinline__ void cast4(const float* __restrict__ in,
                                             __bf16* __restrict__ out, int blk)
{
    const int i = (blk * 256 + threadIdx.x) * 4;
    const float4 v = *(const float4*)(in + i);
    bf16x4 o;
    o[0] = (__bf16)v.x; o[1] = (__bf16)v.y; o[2] = (__bf16)v.z; o[3] = (__bf16)v.w;
    *(bf16x4*)(out + i) = o;
}

static __device__ __forceinline__ void weff4(const float* __restrict__ W,
                                             const float* __restrict__ Bm,
                                             const float* __restrict__ Am,
                                             __bf16* __restrict__ out, int blk)
{
    const int idx = (blk * 256 + threadIdx.x) * 4;
    const int o = idx / D_, i = idx - o * D_;
    const float4 w = *(const float4*)(W + idx);
    float sx = 0.f, sy = 0.f, sz = 0.f, sw = 0.f;
#pragma unroll
    for (int r = 0; r < 8; ++r) {
        const float b = Bm[o * 8 + r];
        const float4 a = *(const float4*)(Am + r * D_ + i);
        sx += b * a.x; sy += b * a.y; sz += b * a.z; sw += b * a.w;
    }
    bf16x4 ov;
    ov[0] = (__bf16)(w.x + 2.f * sx);
    ov[1] = (__bf16)(w.y + 2.f * sy);
    ov[2] = (__bf16)(w.z + 2.f * sz);
    ov[3] = (__bf16)(w.w + 2.f * sw);
    *(bf16x4*)(out + idx) = ov;
}

static __device__ __forceinline__ void count_mask(const int* __restrict__ maskb,
                                                  int* __restrict__ Nv)
{
    const int tid = threadIdx.x, lane = tid & 63, wid = tid >> 6;
    const int4 mv = *(const int4*)(maskb + tid * 4);
    int c = (mv.x != 0) + (mv.y != 0) + (mv.z != 0) + (mv.w != 0);
#pragma unroll
    for (int off = 32; off > 0; off >>= 1) c += __shfl_down(c, off);
    __shared__ int w4[4];
    if (lane == 0) w4[wid] = c;
    __syncthreads();
    if (tid == 0) *Nv = w4[0] + w4[1] + w4[2] + w4[3];
}

__global__ __launch_bounds__(256) void prologue_kernel(
    const float* __restrict__ text, const float* __restrict__ regions,
    const int* __restrict__ mask,
    const float* __restrict__ Wq, const float* __restrict__ Aq, const float* __restrict__ Bq,
    const float* __restrict__ Wv, const float* __restrict__ Av, const float* __restrict__ Bv,
    const float* __restrict__ Wk, const float* __restrict__ Wo,
    const float* __restrict__ gq, const float* __restrict__ bq,
    const float* __restrict__ gkv, const float* __restrict__ bkv,
    __bf16* __restrict__ tq, __bf16* __restrict__ rk, __bf16* __restrict__ regb,
    __bf16* __restrict__ Weq, __bf16* __restrict__ Wev,
    __bf16* __restrict__ Wkb, __bf16* __restrict__ Wob,
    int* __restrict__ NvArr)
{
    int bx = blockIdx.x;
    if (bx < B_ * L_) { ln_row(text + (size_t)bx * D_, gq, bq, tq + (size_t)bx * D_); return; }
    bx -= B_ * L_;
    if (bx < B_ * N_) {
        const int b = bx >> 10, n = bx & (N_ - 1);
        ln_cast_region(regions + (size_t)bx * D_, mask + b * N_, n, gkv, bkv,
                       rk + (size_t)b * N_ * D_, regb + (size_t)b * N_ * D_);
        return;
    }
    bx -= B_ * N_;
    if (bx < 576) { weff4(Wq, Bq, Aq, Weq, bx); return; }
    bx -= 576;
    if (bx < 576) { weff4(Wv, Bv, Av, Wev, bx); return; }
    bx -= 576;
    if (bx < 576) { cast4(Wk, Wkb, bx); return; }
    bx -= 576;
    if (bx < 576) { cast4(Wo, Wob, bx); return; }
    bx -= 576;
    count_mask(mask + bx * N_, NvArr + bx);
}

// ---------------- LDS-staged 128x128 GEMM: 3-buffer counted-vmcnt pipeline ----------------
// T4 recipe: stage(t+2) each step, wait vmcnt(4) + raw s_barrier (never 0 till last step).
// LDS tile [128][32] bf16, slot-swizzled (chunk c at slot c ^ ((row>>1)&3), pre-swizzled src).
// C[m][o] = sum_k A[m][k]*W[o][k]
// EPI==0: bf16 row-major | EPI==1: bf16 transposed (B,H,HD,N) | EPI==2: +resid+bias fp32 | EPI==3: *QK_SCALE bf16
template <int EPI, typename CT>
static __device__ __forceinline__ void gemm_body(__bf16* sm,
                                                 const __bf16* __restrict__ A,
                                                 const __bf16* __restrict__ W,
                                                 CT* __restrict__ C,
                                                 const float* __restrict__ resid,
                                                 const float* __restrict__ bias,
                                                 int mb0, int nb0)
{
    const int tid = threadIdx.x, wid = tid >> 6, lane = tid & 63;
    const int lr = lane & 15, g = lane >> 4;
    const int wm = wid >> 1, wn = wid & 1;
    const int NSTEP = D_ / 32;   // 24

    auto skey2 = [](int row) { return (row >> 1) & 3; };

    auto stage = [&](int kb, int buf) {
        __bf16* as = sm + buf * 8192;
        __bf16* bs = as + 4096;
#pragma unroll
        for (int j = 0; j < 2; ++j) {
            const int s = wid * 64 + lane + j * 256;
            const int row = s >> 2;
            const int c = (s & 3) ^ skey2(row);     // pre-swizzled source chunk
            const int dst = (wid * 64 + j * 256) * 8;
            async_cp16(A + (size_t)(mb0 + row) * D_ + kb * 32 + c * 8, as + dst);
            async_cp16(W + (size_t)(nb0 + row) * D_ + kb * 32 + c * 8, bs + dst);
        }
    };

    f32x4 acc[4][4] = {};

    stage(0, 0);
    stage(1, 1);

    for (int kb = 0; kb < NSTEP; ++kb) {
        if (kb < NSTEP - 1) asm volatile("s_waitcnt vmcnt(4)" ::: "memory");
        else                asm volatile("s_waitcnt vmcnt(0)" ::: "memory");
        __builtin_amdgcn_s_barrier();

        if (kb + 2 < NSTEP) stage(kb + 2, (kb + 2) % 3);

        const __bf16* as = sm + (kb % 3) * 8192;
        const __bf16* bs = as + 4096;
        bf16x8 av[4], wv[4];
#pragma unroll
        for (int mi = 0; mi < 4; ++mi) {
            const int row = wm * 64 + mi * 16 + lr;
            av[mi] = *(const bf16x8*)(as + row * 32 + (g ^ skey2(row)) * 8);
        }
#pragma unroll
        for (int oi = 0; oi < 4; ++oi) {
            const int row = wn * 64 + oi * 16 + lr;
            wv[oi] = *(const bf16x8*)(bs + row * 32 + (g ^ skey2(row)) * 8);
        }
        __builtin_amdgcn_s_setprio(1);
#pragma unroll
        for (int mi = 0; mi < 4; ++mi)
#pragma unroll
            for (int oi = 0; oi < 4; ++oi)
                acc[mi][oi] = mfma16(av[mi], wv[oi], acc[mi][oi]);
        __builtin_amdgcn_s_setprio(0);
    }

#pragma unroll
    for (int mi = 0; mi < 4; ++mi) {
#pragma unroll
        for (int oi = 0; oi < 4; ++oi) {
#pragma unroll
            for (int r = 0; r < 4; ++r) {
                const int m = mb0 + wm * 64 + mi * 16 + g * 4 + r;
                const int o = nb0 + wn * 64 + oi * 16 + lr;
                float v = acc[mi][oi][r];
                if (EPI == 2)
                    v += resid[(size_t)m * D_ + o] + bias[o];
                if (EPI == 3)
                    v *= QK_SCALE;
                if (EPI == 1) {
                    const size_t idx =
                        ((size_t)((m >> 10) * H_ + (o >> 6)) * HD_ + (o & 63)) * N_ + (m & (N_ - 1));
                    C[idx] = (CT)v;
                } else {
                    C[(size_t)m * D_ + o] = (CT)v;
                }
            }
        }
    }
}

// Fused Q+K+V projection GEMMs; 1-D grid, XCD-chunked swizzle on the Q part.
__global__ __launch_bounds__(256) void gemm_qkv(const __bf16* __restrict__ tq,
                                                const __bf16* __restrict__ Weq,
                                                __bf16* __restrict__ Qb,
                                                const __bf16* __restrict__ rk,
                                                const __bf16* __restrict__ Wkb,
                                                __bf16* __restrict__ Kb,
                                                const __bf16* __restrict__ regb,
                                                const __bf16* __restrict__ Wev,
                                                __bf16* __restrict__ Vt,
                                                const int* __restrict__ NvArr)
{
    extern __shared__ __bf16 smem[];
    const int gid = blockIdx.x;
    if (gid < 768) {
        const int xcd = gid & 7, pos = gid >> 3;
        const int s = xcd * 96 + pos;          // bijective: 768 = 8*96
        gemm_body<3, __bf16>(smem, tq, Weq, Qb, nullptr, nullptr, (s / 6) * 128, (s % 6) * 128);
    } else if (gid < 960) {
        const int lin = gid - 768;             // 0..191 : 32 M-blocks x 6 ny
        const int m0 = (lin / 6) * 128, ny = (lin % 6) * 128;
        if ((m0 & (N_ - 1)) >= NvArr[m0 >> 10]) return;   // uniform early-exit
        gemm_body<0, __bf16>(smem, rk, Wkb, Kb, nullptr, nullptr, m0, ny);
    } else {
        const int lin = gid - 960;
        const int m0 = (lin / 6) * 128, ny = (lin % 6) * 128;
        if ((m0 & (N_ - 1)) >= NvArr[m0 >> 10]) return;
        gemm_body<1, __bf16>(smem, regb, Wev, Vt, nullptr, nullptr, m0, ny);
    }
}

__global__ __launch_bounds__(256) void gemm_out(const __bf16* __restrict__ A,
                                                const __bf16* __restrict__ W,
                                                float* __restrict__ C,
                                                const float* __restrict__ resid,
                                                const float* __restrict__ bias)
{
    extern __shared__ __bf16 smem[];
    const int xcd = blockIdx.x & 7, pos = blockIdx.x >> 3;
    const int s = xcd * 96 + pos;              // bijective: 768 = 8*96
    gemm_body<2, float>(smem, A, W, C, resid, bias, (s / 6) * 128, (s % 6) * 128);
}

// ---------------- flash attention over COMPACTED keys: 3-buffer counted-vmcnt, 2 q-frags ----------------
// Block = (b, h, 128 q), 4 waves x 32 q. Q pre-scaled by 0.125*log2e (exp2 domain).
// T4 schedule: stage(t+2) after barrier, vmcnt(4) steady / vmcnt(0) last. Incremented staging pointers.
// ssum cross-lane reduction DEFERRED to after the tile loop (per-lane partials in the loop).
// Compaction => validity is (key index < Nv); only LAST tile compares (cndmask to exact 0 after exp).
// No max-tracking: |S|<=~3 for LN'd inputs; fully-masked batch -> Nv=0 -> output 0.
__global__ __launch_bounds__(256, 3) void attn_kernel(const __bf16* __restrict__ Qb,
                                                      const __bf16* __restrict__ Kb,
                                                      const __bf16* __restrict__ Vt,
                                                      const int* __restrict__ NvArr,
                                                      __bf16* __restrict__ ctx)
{
    const int bq = blockIdx.x, h = blockIdx.y, b = blockIdx.z;
    const int tid = threadIdx.x, wid = tid >> 6, lane = tid & 63;
    const int lr = lane & 15, g = lane >> 4;

    const int Nv = NvArr[b];
    const int ntiles = (Nv + 63) >> 6;

    __shared__ __align__(16) __bf16 kbuf[3][4096];   // 64 keys x 64 d, slot-swizzled
    __shared__ __align__(16) __bf16 vbuf[3][4096];   // 64 d x 64 keys, slot-swizzled

    const int hoff = h * HD_;
    const int bN = b * N_;
    const size_t bhHD = ((size_t)b * H_ + h) * HD_;

    // slot-swizzle key: spreads the 16 concurrently-read rows over all 8 slots
    auto skey = [](int row) { return (row & 3) | (((row >> 3) & 1) << 2); };

    // incremented staging pointers (4 loads/stage)
    const int s0 = wid * 64 + lane, s1 = s0 + 256;
    const int row0 = s0 >> 3, row1 = s1 >> 3;
    const int ks0 = (s0 & 7) ^ skey(row0), ks1 = (s1 & 7) ^ skey(row1);
    const __bf16* kc0 = Kb + (size_t)(bN + row0) * D_ + hoff + ks0 * 8;
    const __bf16* kc1 = Kb + (size_t)(bN + row1) * D_ + hoff + ks1 * 8;
    const __bf16* vc0 = Vt + (bhHD + row0) * N_ + ks0 * 8;
    const __bf16* vc1 = Vt + (bhHD + row1) * N_ + ks1 * 8;
    const int d0 = (wid * 64) * 8, d1 = (wid * 64 + 256) * 8;
    int stage_t = 0;

    auto stage = [&]() {
        const int bsel = stage_t % 3;
        async_cp16(kc0, &kbuf[bsel][d0]);
        async_cp16(kc1, &kbuf[bsel][d1]);
        async_cp16(vc0, &vbuf[bsel][d0]);
        async_cp16(vc1, &vbuf[bsel][d1]);
        kc0 += 64 * D_; kc1 += 64 * D_; vc0 += 64; vc1 += 64;
        ++stage_t;
    };

    const int q0 = bq * 128 + wid * 32;
    bf16x8 qa[2][2];
#pragma unroll
    for (int qf = 0; qf < 2; ++qf) {
        const __bf16* qptr = Qb + ((size_t)b * L_ + q0 + qf * 16 + lr) * D_ + hoff + g * 8;
        qa[qf][0] = *(const bf16x8*)(qptr);
        qa[qf][1] = *(const bf16x8*)(qptr + 32);
    }

    f32x4 acc[2][4] = {};
    float ssum[2] = {0.f, 0.f};   // per-lane partials; cross-lane reduce deferred to epilogue

    if (ntiles > 0) {
        stage();
        if (ntiles > 1) stage();

        for (int t = 0; t < ntiles; ++t) {
            if (t < ntiles - 1) asm volatile("s_waitcnt vmcnt(4)" ::: "memory");
            else                asm volatile("s_waitcnt vmcnt(0)" ::: "memory");
            __builtin_amdgcn_s_barrier();

            if (t + 2 < ntiles) stage();

            const __bf16* kb = kbuf[t % 3];
            const __bf16* vb = vbuf[t % 3];

            // K fragments: rows permuted so lane's S values == its PV A-fragment keys
            bf16x8 kf[4][2];
#pragma unroll
            for (int kt = 0; kt < 4; ++kt) {
                const int row = (kt >> 1) * 32 + (lr >> 2) * 8 + (kt & 1) * 4 + (lr & 3);
                const int kx = skey(row);
#pragma unroll
                for (int kc = 0; kc < 2; ++kc)
                    kf[kt][kc] = *(const bf16x8*)((const char*)kb + row * 128 + ((((kc * 4) + g) ^ kx) << 4));
            }

            const bool lastTile = (t == ntiles - 1);

            bf16x8 pa[2][2];
#pragma unroll
            for (int qf = 0; qf < 2; ++qf) {
                // S^T = K·Q^T : lane holds q=lr, keys (kt>>1)*32 + g*8 + (kt&1)*4 + r
                f32x4 s4[4];
                __builtin_amdgcn_s_setprio(1);
#pragma unroll
                for (int kt = 0; kt < 4; ++kt) {
                    f32x4 z = {};
                    s4[kt] = mfma16(kf[kt][0], qa[qf][0], z);
                    s4[kt] = mfma16(kf[kt][1], qa[qf][1], s4[kt]);
                }
                __builtin_amdgcn_s_setprio(0);

                // exp2-domain no-max softmax; last tile zeroes pad keys (exact 0)
                float p[4][4];
                float tsum = 0.f;
                if (lastTile) {
#pragma unroll
                    for (int kt = 0; kt < 4; ++kt) {
                        const int jb = t * 64 + (kt >> 1) * 32 + g * 8 + (kt & 1) * 4;
#pragma unroll
                        for (int r = 0; r < 4; ++r) {
                            const float e = exp2fast(s4[kt][r]);
                            p[kt][r] = (jb + r < Nv) ? e : 0.f;
                            tsum += p[kt][r];
                        }
                    }
                } else {
#pragma unroll
                    for (int kt = 0; kt < 4; ++kt)
#pragma unroll
                        for (int r = 0; r < 4; ++r) {
                            p[kt][r] = exp2fast(s4[kt][r]);
                            tsum += p[kt][r];
                        }
                }
                ssum[qf] += tsum;   // per-lane partial; reduce across lanes at the end

                // pack P into PV A-fragments (no cross-lane needed by construction)
#pragma unroll
                for (int c = 0; c < 2; ++c) {
                    union { u32 w[4]; bf16x8 v; } pu;
#pragma unroll
                    for (int m = 0; m < 4; ++m) {
                        const int kt = 2 * c + (m >> 1);
                        pu.w[m] = pkbf(p[kt][2 * (m & 1)], p[kt][2 * (m & 1) + 1]);
                    }
                    pa[qf][c] = pu.v;
                }
            }

            __builtin_amdgcn_s_setprio(1);
#pragma unroll
            for (int dt = 0; dt < 4; ++dt) {
                const int d = dt * 16 + lr;
                const int vx = skey(d);
#pragma unroll
                for (int c = 0; c < 2; ++c) {
                    const bf16x8 vf = *(const bf16x8*)((const char*)vb + d * 128 + ((((c * 4) + g) ^ vx) << 4));
                    acc[0][dt] = mfma16(pa[0][c], vf, acc[0][dt]);
                    acc[1][dt] = mfma16(pa[1][c], vf, acc[1][dt]);
                }
            }
            __builtin_amdgcn_s_setprio(0);
        }
    }

#pragma unroll
    for (int qf = 0; qf < 2; ++qf) {
        // deferred cross-lane reduction: lane's q is lr; sum partials over the 4 g-groups x 2 halves
        ssum[qf] += __shfl_xor(ssum[qf], 16);
        ssum[qf] += __shfl_xor(ssum[qf], 32);
        const float inv = (ssum[qf] > 0.f) ? 1.f / ssum[qf] : 0.f;
        float iv[4];
#pragma unroll
        for (int r = 0; r < 4; ++r) iv[r] = __shfl(inv, g * 4 + r);
#pragma unroll
        for (int dt = 0; dt < 4; ++dt)
#pragma unroll
            for (int r = 0; r < 4; ++r) {
                const int q = q0 + qf * 16 + g * 4 + r;
                ctx[((size_t)b * L_ + q) * D_ + hoff + dt * 16 + lr] = (__bf16)(acc[qf][dt][r] * iv[r]);
            }
    }
}

extern "C" void kernel_launch(void* const* d_in, const int* in_sizes, int n_in,
                              void* d_out, int out_size, void* d_ws, size_t ws_size,
                              hipStream_t stream)
{
    const float* text    = (const float*)d_in[0];
    const float* regions = (const float*)d_in[1];
    const int*   mask    = (const int*)d_in[2];
    const float* Wq  = (const float*)d_in[3];
    const float* Aq  = (const float*)d_in[4];
    const float* Bq  = (const float*)d_in[5];
    const float* Wk  = (const float*)d_in[6];
    const float* Wv  = (const float*)d_in[7];
    const float* Av  = (const float*)d_in[8];
    const float* Bv  = (const float*)d_in[9];
    const float* Wo  = (const float*)d_in[10];
    const float* bo  = (const float*)d_in[11];
    const float* gq  = (const float*)d_in[12];
    const float* bq  = (const float*)d_in[13];
    const float* gkv = (const float*)d_in[14];
    const float* bkv = (const float*)d_in[15];

    const size_t BLD = (size_t)B_ * L_ * D_;
    const size_t BND = (size_t)B_ * N_ * D_;
    const size_t DD  = (size_t)D_ * D_;
    __bf16* ws   = (__bf16*)d_ws;
    __bf16* tq   = ws;                 // BLD
    __bf16* rk   = tq + BLD;           // BND (compacted rows)
    __bf16* Qb   = rk + BND;           // BLD
    __bf16* Kb   = Qb + BLD;           // BND (compacted rows)
    __bf16* Vt   = Kb + BND;           // BND (compacted cols)
    __bf16* ctx  = Vt + BND;           // BLD
    __bf16* regb = ctx + BLD;          // BND (compacted rows)
    __bf16* Weq  = regb + BND;         // DD
    __bf16* Wev  = Weq + DD;           // DD
    __bf16* Wkb  = Wev + DD;           // DD
    __bf16* Wob  = Wkb + DD;           // DD
    int* NvArr   = (int*)(Wob + DD);   // B ints

    const int smB = 49152;  // 3-buffer dynamic LDS for gemm kernels
    const int nProBlocks = B_ * L_ + B_ * N_ + 576 * 4 + B_;

    prologue_kernel<<<dim3(nProBlocks), 256, 0, stream>>>(
        text, regions, mask, Wq, Aq, Bq, Wv, Av, Bv, Wk, Wo,
        gq, bq, gkv, bkv, tq, rk, regb, Weq, Wev, Wkb, Wob, NvArr);
    gemm_qkv<<<dim3(1152), 256, smB, stream>>>(tq, Weq, Qb, rk, Wkb, Kb, regb, Wev, Vt, NvArr);
    attn_kernel<<<dim3(L_ / 128, H_, B_), 256, 0, stream>>>(Qb, Kb, Vt, NvArr, ctx);
    gemm_out<<<dim3(768), 256, smB, stream>>>(ctx, Wob, (float*)d_out, text, bo);
}